// Round 15
// baseline (151.592 us; speedup 1.0000x reference)
//
#include <hip/hip_runtime.h>
#include <hip/hip_bf16.h>

#define N_ 8
#define C_ 256
#define HW_ 4096
#define CNT_ (C_*HW_)

typedef __attribute__((ext_vector_type(8))) short bf16x8;
typedef __attribute__((ext_vector_type(4))) float f32x4;
typedef __attribute__((ext_vector_type(16))) float f32x16;
typedef __attribute__((ext_vector_type(4))) int i32x4;
typedef __attribute__((ext_vector_type(8))) int i32x8;

__device__ inline float exp2fast(float x){ return __builtin_amdgcn_exp2f(x); }

__device__ inline unsigned short f2bf(float f){
  union{float f; unsigned u;} v; v.f=f;
  unsigned r = v.u + 0x7fff + ((v.u>>16)&1);
  return (unsigned short)(r>>16);
}
__device__ inline float bf2f(unsigned short h){
  union{unsigned u; float f;} v; v.u = ((unsigned)h)<<16; return v.f;
}

__device__ inline f32x4 mfma16(bf16x8 a, bf16x8 b, f32x4 c){
  return __builtin_amdgcn_mfma_f32_16x16x32_bf16(a,b,c,0,0,0);
}
// MX-scaled fp8 K=64 MFMA, scales = 1.0 (E8M0 127), fmt 0 = fp8 e4m3
__device__ inline f32x16 mfma_mx(i32x8 a, i32x8 b, f32x16 c){
  return __builtin_amdgcn_mfma_scale_f32_32x32x64_f8f6f4(a, b, c, 0, 0, 0, 127, 0, 127);
}

__device__ inline i32x8 ld2x4(const char* p){
  i32x4 a = *(const i32x4*)p;
  i32x4 b = *(const i32x4*)(p+16);
  i32x8 r;
  r[0]=a[0]; r[1]=a[1]; r[2]=a[2]; r[3]=a[3];
  r[4]=b[0]; r[5]=b[1]; r[6]=b[2]; r[7]=b[3];
  return r;
}

#define GLL16(gp, lp) __builtin_amdgcn_global_load_lds( \
    (__attribute__((address_space(1))) void*)(gp), \
    (__attribute__((address_space(3))) void*)(lp), 16, 0, 0)

// ---------------- prologue kernel: weight cvt + bias concat + LN stats stage 1 --------
__global__ void k_pre(const float* __restrict__ wq, const float* __restrict__ wk,
                      const float* __restrict__ wv, const float* __restrict__ wo,
                      const float* __restrict__ bq, const float* __restrict__ bk,
                      unsigned short* __restrict__ dst, float* __restrict__ bqk,
                      const float* __restrict__ x, float2* __restrict__ part){
  int bid = blockIdx.x, t = threadIdx.x;
  if (bid < 1024){
    int i = bid*256 + t;
    const float* s = (i < 65536) ? wq : (i < 131072) ? wk : (i < 196608) ? wv : wo;
    dst[i] = f2bf(s[i & 65535]);
    return;
  }
  if (bid == 1024){
    bqk[t] = bq[t];
    bqk[256+t] = bk[t];
    return;
  }
  int cid = bid - 1025;
  int n = cid >> 8, chunk = cid & 255;
  const float4* p = (const float4*)(x + (size_t)n*CNT_ + (size_t)chunk*4096);
  float s=0.f, s2=0.f;
  #pragma unroll
  for(int i=0;i<4;i++){
    float4 v = p[t + 256*i];
    s  += v.x+v.y+v.z+v.w;
    s2 += v.x*v.x+v.y*v.y+v.z*v.z+v.w*v.w;
  }
  #pragma unroll
  for(int o=32;o;o>>=1){ s += __shfl_down(s,o); s2 += __shfl_down(s2,o); }
  __shared__ float sh[4], sh2[4];
  int lane = t&63, wid = t>>6;
  if(lane==0){ sh[wid]=s; sh2[wid]=s2; }
  __syncthreads();
  if(t==0){
    float2 r; r.x = sh[0]+sh[1]+sh[2]+sh[3]; r.y = sh2[0]+sh2[1]+sh2[2]+sh2[3];
    part[cid] = r;
  }
}

// ---------------- normalize + transpose to NHWC bf16 (stats stage-2 inlined) ----------------
__global__ void k_norm(const float* __restrict__ x, const float* __restrict__ lnw,
                       const float* __restrict__ lnb, const float2* __restrict__ part,
                       unsigned short* __restrict__ nx){
  __shared__ float tile[64][65];
  __shared__ float2 stsh;
  int n = blockIdx.z, c0 = blockIdx.y*64, p0 = blockIdx.x*64;
  int t = threadIdx.x, col = t&63, rw = t>>6;
  {
    float2 v = part[n*256 + t];
    float s = v.x, s2 = v.y;
    #pragma unroll
    for(int o=32;o;o>>=1){ s += __shfl_down(s,o); s2 += __shfl_down(s2,o); }
    __shared__ float sh[4], sh2[4];
    int lane = t&63, wid = t>>6;
    if(lane==0){ sh[wid]=s; sh2[wid]=s2; }
    __syncthreads();
    if(t==0){
      s = sh[0]+sh[1]+sh[2]+sh[3];
      s2 = sh2[0]+sh2[1]+sh2[2]+sh2[3];
      float mean = s * (1.f/(float)CNT_);
      float var  = s2 * (1.f/(float)CNT_) - mean*mean;
      float2 r; r.x = mean; r.y = rsqrtf(var + 1e-5f);
      stsh = r;
    }
    __syncthreads();
  }
  float mu = stsh.x, rs = stsh.y;
  #pragma unroll
  for(int pass=0; pass<16; pass++){
    int row = pass*4 + rw;
    size_t gi = (size_t)(c0+row)*HW_ + (p0+col);
    float v = x[(size_t)n*CNT_ + gi];
    tile[row][col] = (v - mu)*rs*lnw[gi] + lnb[gi];
  }
  __syncthreads();
  #pragma unroll
  for(int pass=0; pass<16; pass++){
    int prow = pass*4 + rw;
    nx[((size_t)n*HW_ + p0+prow)*C_ + c0 + col] = f2bf(tile[col][prow]);
  }
}

// ---------------- merged QKV projection: one dispatch, two roles ----------------
// blocks [0,1024): QK  — A=nx[n], B=[wq;wk], bias=bqk (col), out fp8 [seq][512]
// blocks [1024,1536): V — A=wv,    B=nx[n],  bias=bv  (row), out fp8 [dim][seq]
__device__ inline void g2_stage(const char* A, const char* B, char* buf,
                                int w, int r8, int s8, int i0, int c0, int kb0){
  int sl = (s8 ^ (r8&7)) << 4;
  #pragma unroll
  for(int q=0;q<4;q++){
    int row = w*32 + q*8 + r8;
    GLL16(A + (size_t)(i0+row)*512 + kb0 + sl, buf + w*4096 + q*1024);
    GLL16(B + (size_t)(c0+row)*512 + kb0 + sl, buf + 16384 + w*4096 + q*1024);
  }
}

__global__ __launch_bounds__(256, 2) void k_gemmQKV(
    const unsigned short* __restrict__ nx,
    const unsigned short* __restrict__ wqk, const float* __restrict__ bqk,
    unsigned char* __restrict__ qk8,
    const unsigned short* __restrict__ wv, const float* __restrict__ bv,
    unsigned char* __restrict__ v8){
  __shared__ __align__(16) char lds[65536];
  int bid = blockIdx.x;
  const char* A; const char* B; const float* bias; float scale;
  unsigned char* O8; int ldo, bias_row, i0, c0;
  const char* nxb = (const char*)nx;
  if (bid < 1024){
    int n = bid >> 7, r = bid & 127;
    i0 = (r & 31)*128; c0 = (r >> 5)*128;
    A = nxb + (size_t)n*(HW_*512);
    B = (const char*)wqk;
    bias = bqk; bias_row = 0; scale = 0.3002807f;   // sqrt(log2e/16)
    O8 = qk8 + (size_t)n*HW_*512; ldo = 512;
  } else {
    int vid = bid - 1024;
    int n = vid >> 6, r = vid & 63;
    i0 = (r & 1)*128; c0 = (r >> 1)*128;
    A = (const char*)wv;
    B = nxb + (size_t)n*(HW_*512);
    bias = bv; bias_row = 1; scale = 1.0f;
    O8 = v8 + (size_t)n*(size_t)CNT_; ldo = HW_;
  }
  int t = threadIdx.x, w = t>>6, l = t&63;
  int wr = w>>1, wc = w&1, ri = l&15, kq = l>>4;
  int r8 = l>>3, s8 = l&7;

  f32x4 acc[4][4];
  #pragma unroll
  for(int m=0;m<4;m++)
    #pragma unroll
    for(int nn=0;nn<4;nn++)
      #pragma unroll
      for(int r=0;r<4;r++) acc[m][nn][r] = 0.f;

  g2_stage(A, B, lds, w, r8, s8, i0, c0, 0);
  __syncthreads();

  for(int kt=0; kt<4; ++kt){
    char* buf = lds + (kt&1)*32768;
    if (kt < 3) g2_stage(A, B, lds + ((kt&1)^1)*32768, w, r8, s8, i0, c0, (kt+1)*128);
    __builtin_amdgcn_s_setprio(1);
    #pragma unroll
    for(int kc=0;kc<2;kc++){
      bf16x8 af[4], bfv[4];
      #pragma unroll
      for(int m=0;m<4;m++){
        int row = wr*64 + m*16 + ri;
        af[m] = *(const bf16x8*)(buf + row*128 + ((((kc<<2)|kq) ^ (row&7))<<4));
      }
      #pragma unroll
      for(int nn=0;nn<4;nn++){
        int row = wc*64 + nn*16 + ri;
        bfv[nn] = *(const bf16x8*)(buf + 16384 + row*128 + ((((kc<<2)|kq) ^ (row&7))<<4));
      }
      #pragma unroll
      for(int m=0;m<4;m++)
        #pragma unroll
        for(int nn=0;nn<4;nn++)
          acc[m][nn] = mfma16(af[m], bfv[nn], acc[m][nn]);
    }
    __builtin_amdgcn_s_setprio(0);
    __syncthreads();
  }

  #pragma unroll
  for(int m=0;m<4;m++){
    #pragma unroll
    for(int nn=0;nn<4;nn++){
      #pragma unroll
      for(int r=0;r<4;r++){
        int row = i0 + wr*64 + m*16 + kq*4 + r;
        int col = c0 + wc*64 + nn*16 + ri;
        float d = (acc[m][nn][r] + bias[bias_row ? row : col])*scale;
        unsigned u;
        asm("v_cvt_pk_fp8_f32 %0, %1, %2" : "=v"(u) : "v"(d), "v"(0.f));
        O8[(size_t)row*ldo + col] = (unsigned char)(u & 0xff);
      }
    }
  }
}

// ---------------- output projection with inline j-half merge + residual ----------------
__global__ __launch_bounds__(256, 2) void k_outproj2(
    const unsigned short* __restrict__ wob,
    const unsigned short* __restrict__ pO0, const unsigned short* __restrict__ pO1,
    const float2* __restrict__ pml,
    const float* __restrict__ bo, const float* __restrict__ x,
    float* __restrict__ out){
  __shared__ __align__(16) char lds[65536];
  int n = blockIdx.z;
  const char* A = (const char*)wob;
  const char* B0 = (const char*)(pO0 + (size_t)n*HW_*C_);
  const char* B1 = (const char*)(pO1 + (size_t)n*HW_*C_);
  int t = threadIdx.x, w = t>>6, l = t&63;
  int wr = w>>1, wc = w&1, ri = l&15, kq = l>>4;
  int r8 = l>>3, s8 = l&7;
  int i0 = blockIdx.x*128, c0 = blockIdx.y*128;
  int sl = (s8 ^ (r8&7)) << 4;

  float s0v[4], s1v[4];
  #pragma unroll
  for(int q=0;q<4;q++){
    int row = c0 + w*32 + q*8 + r8;
    float2 ml0 = pml[(size_t)n*HW_ + row];
    float2 ml1 = pml[(size_t)N_*HW_ + (size_t)n*HW_ + row];
    float mN = fmaxf(ml0.x, ml1.x);
    float a0 = exp2fast(ml0.x - mN), a1 = exp2fast(ml1.x - mN);
    float inv = 1.f/(a0*ml0.y + a1*ml1.y);
    s0v[q] = a0*inv; s1v[q] = a1*inv;
  }

  f32x4 acc[4][4];
  #pragma unroll
  for(int m=0;m<4;m++)
    #pragma unroll
    for(int nn=0;nn<4;nn++)
      #pragma unroll
      for(int r=0;r<4;r++) acc[m][nn][r] = 0.f;

  uint4 bl0[4], bl1[4];
  #pragma unroll
  for(int q=0;q<4;q++){
    int row = w*32 + q*8 + r8;
    GLL16(A + (size_t)(i0+row)*512 + sl, lds + w*4096 + q*1024);
    bl0[q] = *(const uint4*)(B0 + (size_t)(c0+row)*512 + sl);
    bl1[q] = *(const uint4*)(B1 + (size_t)(c0+row)*512 + sl);
  }
  #pragma unroll
  for(int q=0;q<4;q++){
    unsigned w0[4] = {bl0[q].x, bl0[q].y, bl0[q].z, bl0[q].w};
    unsigned w1[4] = {bl1[q].x, bl1[q].y, bl1[q].z, bl1[q].w};
    unsigned rr[4];
    #pragma unroll
    for(int j=0;j<4;j++){
      float lo = s0v[q]*bf2f((unsigned short)(w0[j]&0xffff)) + s1v[q]*bf2f((unsigned short)(w1[j]&0xffff));
      float hi = s0v[q]*bf2f((unsigned short)(w0[j]>>16))    + s1v[q]*bf2f((unsigned short)(w1[j]>>16));
      rr[j] = (unsigned)f2bf(lo) | ((unsigned)f2bf(hi)<<16);
    }
    uint4 rw; rw.x=rr[0]; rw.y=rr[1]; rw.z=rr[2]; rw.w=rr[3];
    *(uint4*)(lds + 16384 + w*4096 + q*1024 + l*16) = rw;
  }
  __syncthreads();

  for(int kt=0; kt<4; ++kt){
    char* buf  = lds + (kt&1)*32768;
    char* nbuf = lds + ((kt&1)^1)*32768;
    if (kt < 3){
      int kb0 = (kt+1)*128;
      #pragma unroll
      for(int q=0;q<4;q++){
        int row = w*32 + q*8 + r8;
        GLL16(A + (size_t)(i0+row)*512 + kb0 + sl, nbuf + w*4096 + q*1024);
        bl0[q] = *(const uint4*)(B0 + (size_t)(c0+row)*512 + kb0 + sl);
        bl1[q] = *(const uint4*)(B1 + (size_t)(c0+row)*512 + kb0 + sl);
      }
    }
    __builtin_amdgcn_s_setprio(1);
    #pragma unroll
    for(int kc=0;kc<2;kc++){
      bf16x8 af[4], bfv[4];
      #pragma unroll
      for(int m=0;m<4;m++){
        int row = wr*64 + m*16 + ri;
        af[m] = *(const bf16x8*)(buf + row*128 + ((((kc<<2)|kq) ^ (row&7))<<4));
      }
      #pragma unroll
      for(int nn=0;nn<4;nn++){
        int row = wc*64 + nn*16 + ri;
        bfv[nn] = *(const bf16x8*)(buf + 16384 + row*128 + ((((kc<<2)|kq) ^ (row&7))<<4));
      }
      #pragma unroll
      for(int m=0;m<4;m++)
        #pragma unroll
        for(int nn=0;nn<4;nn++)
          acc[m][nn] = mfma16(af[m], bfv[nn], acc[m][nn]);
    }
    __builtin_amdgcn_s_setprio(0);
    if (kt < 3){
      #pragma unroll
      for(int q=0;q<4;q++){
        unsigned w0[4] = {bl0[q].x, bl0[q].y, bl0[q].z, bl0[q].w};
        unsigned w1[4] = {bl1[q].x, bl1[q].y, bl1[q].z, bl1[q].w};
        unsigned rr[4];
        #pragma unroll
        for(int j=0;j<4;j++){
          float lo = s0v[q]*bf2f((unsigned short)(w0[j]&0xffff)) + s1v[q]*bf2f((unsigned short)(w1[j]&0xffff));
          float hi = s0v[q]*bf2f((unsigned short)(w0[j]>>16))    + s1v[q]*bf2f((unsigned short)(w1[j]>>16));
          rr[j] = (unsigned)f2bf(lo) | ((unsigned)f2bf(hi)<<16);
        }
        uint4 rw; rw.x=rr[0]; rw.y=rr[1]; rw.z=rr[2]; rw.w=rr[3];
        *(uint4*)(nbuf + 16384 + w*4096 + q*1024 + l*16) = rw;
      }
    }
    __syncthreads();
  }

  const float* xr = x + (size_t)n*CNT_;
  float* fout = out + (size_t)n*CNT_;
  #pragma unroll
  for(int m=0;m<4;m++){
    #pragma unroll
    for(int nn=0;nn<4;nn++){
      #pragma unroll
      for(int r=0;r<4;r++){
        int row = i0 + wr*64 + m*16 + kq*4 + r;
        int col = c0 + wc*64 + nn*16 + ri;
        size_t idx = (size_t)row*HW_ + col;
        fout[idx] = acc[m][nn][r] + bo[row] + xr[idx];
      }
    }
  }
}

// ---------------- flash attention: all-fp8 MX (K=64), Q/K interleaved at stride 512 -----
__device__ inline void stage_KV_mx(const char* kb, const char* vb, char* buf,
                                   int w, int l, int j0){
  #pragma unroll
  for(int k=0;k<4;k++){
    int g = w*4 + k;
    int row = g*4 + (l>>4);
    int i = l & 15;
    int sp = (((i>>1) ^ (row&7))<<5) + ((i&1)<<4);
    GLL16(kb + (size_t)(j0+row)*512 + sp, buf + g*1024);
  }
  #pragma unroll
  for(int k=0;k<5;k++){
    int g = w*5 + k;
    int c = g*64 + l;
    int d = c/5; int sg = c - d*5; sg = (sg==4)?0:sg;
    GLL16(vb + (size_t)d*HW_ + j0 + sg*16, buf + 16384 + g*1024);
  }
}

__global__ __launch_bounds__(256, 2) void k_attn8(const unsigned char* __restrict__ qk8,
                                                  const unsigned char* __restrict__ vv,
                                                  unsigned short* __restrict__ pO0,
                                                  unsigned short* __restrict__ pO1,
                                                  float2* __restrict__ pml){
  __shared__ __align__(16) char lds[73728];     // 2 x (16 KB K + 20 KB V)
  int t = threadIdx.x, w = t>>6, l = t&63, hi = l>>5, lo5 = l&31;
  int nb = blockIdx.x & 7, rem = blockIdx.x >> 3;
  int qb = rem >> 1, jh = rem & 1;
  int q0 = qb*128 + w*32;
  const char* qp = (const char*)(qk8 + (size_t)nb*HW_*512);
  const char* kb = qp + 256;           // K columns
  const char* vb = (const char*)(vv + (size_t)nb*(size_t)CNT_);
  int jbase = jh*2048;

  i32x8 qfr[4];
  #pragma unroll
  for(int db=0; db<4; db++)
    qfr[db] = ld2x4(qp + (size_t)(q0+lo5)*512 + db*64 + hi*32);

  f32x16 o[8];
  #pragma unroll
  for(int dt=0;dt<8;dt++){
    #pragma unroll
    for(int r=0;r<16;r++) o[dt][r]=0.f;
  }
  float m = -1e30f, lsum = 0.f;

  stage_KV_mx(kb, vb, lds, w, l, jbase);
  __syncthreads();

  for(int it=0; it<32; ++it){
    char* bufc = lds + (it&1)*36864;
    if (it < 31) stage_KV_mx(kb, vb, lds + ((it&1)^1)*36864, w, l, jbase + (it+1)*64);

    f32x16 Sa, Sb;
    #pragma unroll
    for(int r=0;r<16;r++){ Sa[r]=0.f; Sb[r]=0.f; }
    __builtin_amdgcn_s_setprio(1);
    #pragma unroll
    for(int db=0; db<4; db++){
      int sl = ((db*2+hi) ^ (lo5&7))<<5;
      i32x8 ka  = ld2x4(bufc + lo5*256      + sl);
      i32x8 kb2 = ld2x4(bufc + (32+lo5)*256 + sl);
      Sa = mfma_mx(ka,  qfr[db], Sa);
      Sb = mfma_mx(kb2, qfr[db], Sb);
    }
    __builtin_amdgcn_s_setprio(0);

    float mm[8];
    #pragma unroll
    for(int r=0;r<8;r++) mm[r] = fmaxf(fmaxf(Sa[r],Sa[r+8]), fmaxf(Sb[r],Sb[r+8]));
    mm[0]=fmaxf(mm[0],mm[4]); mm[1]=fmaxf(mm[1],mm[5]);
    mm[2]=fmaxf(mm[2],mm[6]); mm[3]=fmaxf(mm[3],mm[7]);
    float mx = fmaxf(fmaxf(mm[0],mm[1]), fmaxf(mm[2],mm[3]));
    { float mA = mx, mB = mx;
      asm("v_permlane32_swap_b32 %0, %1" : "+v"(mA), "+v"(mB));
      mx = fmaxf(mA, mB); }
    if (!__all(mx <= m + 8.f)){     // THR=8: P <= 256 < fp8 e4m3 max 448
      float mn = fmaxf(m, mx);
      float al = exp2fast(m - mn);
      lsum *= al;
      #pragma unroll
      for(int dt=0;dt<8;dt++) o[dt] = o[dt] * al;
      m = mn;
    }
    float rs = 0.f;
    #pragma unroll
    for(int r=0;r<16;r++){
      Sa[r] = exp2fast(Sa[r]-m); rs += Sa[r];
      Sb[r] = exp2fast(Sb[r]-m); rs += Sb[r];
    }
    { float rA = rs, rB = rs;
      asm("v_permlane32_swap_b32 %0, %1" : "+v"(rA), "+v"(rB));
      lsum += rA + rB; }

    unsigned Aw[4], Bw[4];
    #pragma unroll
    for(int w4=0; w4<4; w4++){
      unsigned ua, ub;
      asm("v_cvt_pk_fp8_f32 %0, %1, %2" : "=v"(ua) : "v"(Sa[4*w4]), "v"(Sa[4*w4+1]));
      asm("v_cvt_pk_fp8_f32 %0, %1, %2 op_sel:[0,0,1]" : "+v"(ua) : "v"(Sa[4*w4+2]), "v"(Sa[4*w4+3]));
      asm("v_cvt_pk_fp8_f32 %0, %1, %2" : "=v"(ub) : "v"(Sb[4*w4]), "v"(Sb[4*w4+1]));
      asm("v_cvt_pk_fp8_f32 %0, %1, %2 op_sel:[0,0,1]" : "+v"(ub) : "v"(Sb[4*w4+2]), "v"(Sb[4*w4+3]));
      Aw[w4] = ua; Bw[w4] = ub;
    }
    #pragma unroll
    for(int w4=0; w4<4; w4++)
      asm("v_permlane32_swap_b32 %0, %1" : "+v"(Aw[w4]), "+v"(Bw[w4]));
    i32x8 P;
    P[0]=Aw[0]; P[1]=Bw[0]; P[2]=Aw[1]; P[3]=Bw[1];
    P[4]=Aw[2]; P[5]=Bw[2]; P[6]=Aw[3]; P[7]=Bw[3];

    __builtin_amdgcn_s_setprio(1);
    #pragma unroll
    for(int dt=0;dt<8;dt++){
      i32x8 vf = ld2x4(bufc + 16384 + (dt*32+lo5)*80 + hi*32);
      o[dt] = mfma_mx(vf, P, o[dt]);
    }
    __builtin_amdgcn_s_setprio(0);
    __syncthreads();
  }

  unsigned short* pb = (jh ? pO1 : pO0) + ((size_t)nb*HW_ + q0 + lo5)*C_;
  #pragma unroll
  for(int dt=0;dt<8;dt++){
    #pragma unroll
    for(int g=0;g<4;g++){
      int d0 = dt*32 + g*8 + hi*4;
      unsigned short h0 = f2bf(o[dt][4*g]);
      unsigned short h1 = f2bf(o[dt][4*g+1]);
      unsigned short h2 = f2bf(o[dt][4*g+2]);
      unsigned short h3 = f2bf(o[dt][4*g+3]);
      uint2 uo; uo.x = (unsigned)h0 | ((unsigned)h1<<16);
      uo.y = (unsigned)h2 | ((unsigned)h3<<16);
      *(uint2*)(pb + d0) = uo;
    }
  }
  if (l < 32){
    float2 ml; ml.x = m; ml.y = lsum;
    pml[(size_t)jh*((size_t)N_*HW_) + (size_t)nb*HW_ + q0 + lo5] = ml;
  }
}

extern "C" void kernel_launch(void* const* d_in, const int* in_sizes, int n_in,
                              void* d_out, int out_size, void* d_ws, size_t ws_size,
                              hipStream_t stream) {
  const float* x   = (const float*)d_in[0];
  const float* lnw = (const float*)d_in[1];
  const float* lnb = (const float*)d_in[2];
  const float* wq  = (const float*)d_in[3];
  const float* bq  = (const float*)d_in[4];
  const float* wk  = (const float*)d_in[5];
  const float* bk  = (const float*)d_in[6];
  const float* wv  = (const float*)d_in[7];
  const float* bv  = (const float*)d_in[8];
  const float* wo  = (const float*)d_in[9];
  const float* bo  = (const float*)d_in[10];
  float* out = (float*)d_out;

  uintptr_t base = (uintptr_t)d_ws;
  float2* part  = (float2*)base;                       // 2048 float2 (16 KB)
  float*  bqk   = (float*)(base + 16384);              // 512 floats
  unsigned short* wqb = (unsigned short*)(base + 18432);
  unsigned short* wvb = wqb + 2*65536;
  unsigned short* wob = wqb + 3*65536;
  unsigned short* nx  = wqb + 4*65536;
  const size_t TEN = (size_t)N_*HW_*C_;
  unsigned short* qkb = nx + TEN;       // fp8 QK [seq][512] = 16.8 MB
  unsigned short* vvb = qkb + TEN;      // fp8 V [dim][seq]
  unsigned short* pO1 = vvb + TEN;      // bf16 partial O, j-half 1
  float2* pml = (float2*)(pO1 + TEN);   // [2][N*HW] float2
  unsigned short* pO0 = nx;             // alias: nx dead after QKV

  k_pre<<<dim3(3073),256,0,stream>>>(wq, wk, wv, wo, bq, bk, wqb, bqk, x, part);
  k_norm<<<dim3(64,4,8),256,0,stream>>>(x, lnw, lnb, part, nx);

  // merged QKV projections: blocks [0,1024) QK, [1024,1536) V
  k_gemmQKV<<<dim3(1536),256,0,stream>>>(nx, wqb, bqk, (unsigned char*)qkb,
                                         wvb, bv, (unsigned char*)vvb);

  k_attn8<<<dim3(512),256,0,stream>>>((const unsigned char*)qkb,
                                      (const unsigned char*)vvb, pO0, pO1, pml);

  k_outproj2<<<dim3(2,32,8),256,0,stream>>>(wob, pO0, pO1, pml, bo, x, out);
}